// Round 4
// baseline (324.849 us; speedup 1.0000x reference)
//
#include <hip/hip_runtime.h>
#include <hip/hip_bf16.h>

#define LRELU_SLOPE 0.2f

typedef __attribute__((ext_vector_type(8))) short short8;
typedef __attribute__((ext_vector_type(4))) float f32x4;

__device__ __forceinline__ unsigned short bf16r(float f) {
    unsigned int u = __builtin_bit_cast(unsigned int, f);
    u += 0x7fffu + ((u >> 16) & 1u);   // RNE
    return (unsigned short)(u >> 16);
}
__device__ __forceinline__ float bf2f(unsigned short u) {
    return __builtin_bit_cast(float, (unsigned int)u << 16);
}

// async global->LDS 16B DMA (guide §5: compiler never auto-emits this)
#define GLD16(g, l)                                                            \
    __builtin_amdgcn_global_load_lds(                                          \
        (const __attribute__((address_space(1))) void*)(g),                    \
        (__attribute__((address_space(3))) void*)(l), 16, 0, 0)

// ---------------- fused preamble: x->bf16 + all W -> WT bf16 transposed + edge count ----------------

#define WTOT 108544  // 65536 + 32768 + 8192 + 2048

__global__ void k_pre(const float* __restrict__ x, unsigned short* __restrict__ Xb,
                      const float* __restrict__ Wa, const float* __restrict__ Wb,
                      const float* __restrict__ Wc, const float* __restrict__ Wd,
                      unsigned short* __restrict__ Ta, unsigned short* __restrict__ Tb,
                      unsigned short* __restrict__ Tc, unsigned short* __restrict__ Td,
                      const int* __restrict__ ei, int* __restrict__ cnt,
                      int XC, int E, int N) {
    int gid = blockIdx.x * blockDim.x + threadIdx.x;
    if (gid < XC) {
        // convert 8 f32 -> 8 bf16 (coalesced float4 x2 -> short8)
        const float4* xp = (const float4*)x + (long)gid * 2;
        float4 a = xp[0], b = xp[1];
        short8 pk;
        pk[0] = (short)bf16r(a.x); pk[1] = (short)bf16r(a.y);
        pk[2] = (short)bf16r(a.z); pk[3] = (short)bf16r(a.w);
        pk[4] = (short)bf16r(b.x); pk[5] = (short)bf16r(b.y);
        pk[6] = (short)bf16r(b.z); pk[7] = (short)bf16r(b.w);
        *(short8*)(Xb + (long)gid * 8) = pk;
        return;
    }
    int id = gid - XC;
    if (id < WTOT) {
        const float* W; unsigned short* T; int K, Nc;
        if (id < 65536)       { W = Wa; T = Ta; K = 256; Nc = 256; }
        else if (id < 98304)  { id -= 65536;  W = Wb; T = Tb; K = 256; Nc = 128; }
        else if (id < 106496) { id -= 98304;  W = Wc; T = Tc; K = 128; Nc = 64; }
        else                  { id -= 106496; W = Wd; T = Td; K = 64;  Nc = 32; }
        int n = id / K, k = id % K;
        T[id] = bf16r(W[(long)k * Nc + n]);
        return;
    }
    int e = id - WTOT;
    if (e >= E + N) return;
    int dst = (e < E) ? ei[E + e] : (e - E);
    atomicAdd(&cnt[dst], 1);
}

// ---------------- CSR scan + scatter ----------------

__global__ void k_scan_blk(const int* __restrict__ cnt, int* __restrict__ offs,
                           int* __restrict__ bsum, int N) {
    __shared__ int temp[1024];
    int t = threadIdx.x;
    int gi = blockIdx.x * 1024 + t;
    int v = (gi < N) ? cnt[gi] : 0;
    temp[t] = v;
    __syncthreads();
    for (int o = 1; o < 1024; o <<= 1) {
        int x = (t >= o) ? temp[t - o] : 0;
        __syncthreads();
        temp[t] += x;
        __syncthreads();
    }
    if (gi < N) offs[gi] = temp[t] - v;
    if (t == 1023) bsum[blockIdx.x] = temp[1023];
}

__global__ void k_scan(const int* __restrict__ cnt, int* __restrict__ offs, int N) {
    __shared__ int temp[1024];
    __shared__ int carry_s;
    int t = threadIdx.x;
    if (t == 0) carry_s = 0;
    __syncthreads();
    for (int base = 0; base < N; base += 1024) {
        int v = (base + t < N) ? cnt[base + t] : 0;
        temp[t] = v;
        __syncthreads();
        for (int o = 1; o < 1024; o <<= 1) {
            int x = (t >= o) ? temp[t - o] : 0;
            __syncthreads();
            temp[t] += x;
            __syncthreads();
        }
        int incl = temp[t];
        int carry = carry_s;
        if (base + t < N) offs[base + t] = carry + incl - v;
        __syncthreads();
        if (t == 1023) carry_s = carry + temp[1023];
        __syncthreads();
    }
    if (t == 0) offs[N] = carry_s;
}

__global__ void k_scan_add(int* __restrict__ offs, const int* __restrict__ bpre,
                           int* __restrict__ wp, int N, int nb) {
    int gi = blockIdx.x * blockDim.x + threadIdx.x;
    if (gi < N) {
        int v = offs[gi] + bpre[gi >> 10];
        offs[gi] = v;
        wp[gi] = v;
    } else if (gi == N) {
        offs[N] = bpre[nb];
    }
}

__global__ void k_scatter(const int* __restrict__ ei, int* __restrict__ wp,
                          int* __restrict__ adj, int E, int N) {
    int e = blockIdx.x * blockDim.x + threadIdx.x;
    if (e >= E + N) return;
    int srcn = (e < E) ? ei[e] : (e - E);
    int dst  = (e < E) ? ei[E + e] : (e - E);
    int pos = atomicAdd(&wp[dst], 1);
    adj[pos] = srcn;
}

// ---------------- MFMA GEMM + fused s/d scores ----------------
// r14: A AND B staged via global_load_lds width-16 (linear LDS dest, pre-swizzled
// global source; XOR-swizzled ds_read_b128 frag reads). KT == full K, so tiles
// are contiguous in global -> perfectly coalesced DMA. This removed k_mgemm from
// the top-5 (was 46.5us at 29% occupancy with per-lane register prefetch).

template<int BN, int KT, int GX>
__global__ __launch_bounds__(256) void k_mgemm(const unsigned short* __restrict__ Ab,
                                               const unsigned short* __restrict__ WT,
                                               unsigned short* __restrict__ Cb,
                                               const float* __restrict__ a_src,
                                               const float* __restrict__ a_dst,
                                               float* __restrict__ sbuf,
                                               float* __restrict__ dbuf,
                                               int M, int Nc, int H, int RB) {
    constexpr int KITER = KT / 32;        // K-steps (also A-stage iters)
    constexpr int NBF = BN / 16;          // B fragments per wave
    constexpr int CPR = BN / 32;          // 32-col chunks per row (epilogue)
    constexpr int SP  = BN + 8;           // epilogue LDS row stride
    constexpr int ASH = 64 * KT;          // A shorts
    constexpr int BSH = BN * KT;          // B shorts
    constexpr int EPIL = 64 * SP;
    constexpr int LBSZ = (ASH + BSH) > EPIL ? (ASH + BSH) : EPIL;
    constexpr int SHC = (KT == 256) ? 5 : (KT == 128 ? 4 : 3);  // log2(chunks per row)
    constexpr int BIT = BN * KT / 2048;   // B-stage iters
    __shared__ __align__(16) unsigned short LB[LBSZ];

    // swizzled decode: id = xcd + 8*( (rb/8)*GX + ct ), rb = (q/GX)*8 + xcd
    int id = blockIdx.x;
    int xcd = id & 7;
    int q  = id >> 3;
    int ct = q % GX;
    int rb = (q / GX) * 8 + xcd;
    if (rb >= RB) return;
    int bm = rb * 64, bn = ct * BN;

    int t = threadIdx.x;
    int wv = t >> 6, l = t & 63;
    int row_in = l & 15, quad = l >> 4;
    char* LBb = (char*)LB;

    // ---- stage A tile (64 x KT bf16, contiguous in global) via DMA ----
    long abyte = (long)bm * (KT * 2);
    long mbyte = (long)M * (KT * 2);
    const char* Agb = (const char*)Ab;
#pragma unroll
    for (int i = 0; i < KITER; ++i) {
        int c = i * 256 + t;
        int cs = c ^ ((c >> SHC) & 7);
        long gb = abyte + (long)cs * 16;
        if (gb >= mbyte) gb = abyte;            // OOB tail rows: garbage, masked at store
        GLD16(Agb + gb, LBb + (i * 256 + wv * 64) * 16);
    }
    // ---- stage B tile (BN x KT bf16, contiguous in WT) via DMA ----
    const char* WTb = (const char*)WT + (long)bn * (KT * 2);
#pragma unroll
    for (int i = 0; i < BIT; ++i) {
        int c = i * 256 + t;
        int cs = c ^ ((c >> SHC) & 7);
        GLD16(WTb + (long)cs * 16, LBb + ASH * 2 + (i * 256 + wv * 64) * 16);
    }
    asm volatile("s_waitcnt vmcnt(0)" ::: "memory");
    __syncthreads();

    f32x4 acc[NBF];
#pragma unroll
    for (int j = 0; j < NBF; ++j) acc[j] = (f32x4){0.f, 0.f, 0.f, 0.f};

    // ---- K loop: pure LDS -> MFMA, swizzled b128 reads ----
    int arow = wv * 16 + row_in;
#pragma unroll
    for (int ki = 0; ki < KITER; ++ki) {
        int aoff = (arow * (KT * 2) + ki * 64 + quad * 16) ^ ((arow & 7) << 4);
        short8 av = *(const short8*)(LBb + aoff);
#pragma unroll
        for (int f = 0; f < NBF; ++f) {
            int bcol = f * 16 + row_in;
            int boff = ASH * 2 + ((bcol * (KT * 2) + ki * 64 + quad * 16) ^ ((bcol & 7) << 4));
            short8 bv = *(const short8*)(LBb + boff);
            acc[f] = __builtin_amdgcn_mfma_f32_16x16x32_bf16(av, bv, acc[f], 0, 0, 0);
        }
    }
    __syncthreads();   // before LDS reuse for epilogue

    // ---- epilogue: LDS repack (bf16) -> coalesced stores + fused s/d ----
#pragma unroll
    for (int r = 0; r < 4; ++r)
#pragma unroll
        for (int f = 0; f < NBF; ++f)
            LB[(wv * 16 + quad * 4 + r) * SP + f * 16 + row_in] = bf16r(acc[f][r]);
    __syncthreads();

    int rr = t / CPR, cc = t % CPR;
    if (rr < 64) {
        int grow = bm + rr;
        int colb = bn + cc * 32;
        if (grow < M && colb < Nc) {
            const unsigned short* ep = &LB[rr * SP + cc * 32];
            short8 v0 = *(const short8*)(ep);
            short8 v1 = *(const short8*)(ep + 8);
            short8 v2 = *(const short8*)(ep + 16);
            short8 v3 = *(const short8*)(ep + 24);
            unsigned short* cp = &Cb[(long)grow * Nc + colb];
            *(short8*)(cp)      = v0;
            *(short8*)(cp + 8)  = v1;
            *(short8*)(cp + 16) = v2;
            *(short8*)(cp + 24) = v3;
            int hd = colb >> 5;   // 32 channels per head
            const float* ap = a_src + hd * 32;
            const float* dp = a_dst + hd * 32;
            float ss = 0.f, dd = 0.f;
#pragma unroll
            for (int u = 0; u < 8; ++u) {
                float va = bf2f((unsigned short)v0[u]); ss += va * ap[u];      dd += va * dp[u];
                float vb = bf2f((unsigned short)v1[u]); ss += vb * ap[8 + u];  dd += vb * dp[8 + u];
                float vc = bf2f((unsigned short)v2[u]); ss += vc * ap[16 + u]; dd += vc * dp[16 + u];
                float vd = bf2f((unsigned short)v3[u]); ss += vd * ap[24 + u]; dd += vd * dp[24 + u];
            }
            sbuf[(long)grow * H + hd] = ss;
            dbuf[(long)grow * H + hd] = dd;
        }
    }
}

// ---------------- fused aggregate: max-free softmax, single pass ----------------
// r15: 8-edge batches, branchless. Previous 4-wide loop had only 4 gathers in
// flight (VGPR=32) and a per-batch serial chain adj->swizzle->gather (~900cy);
// nothing above 42% -> latency-bound. Now each quad-lane owns 2 edges; all 8 sn
// broadcasts + 8 h-gathers issue back-to-back before any exp/FMA consumes them.
// Tail slots clamp to end-1 (L1-hot duplicate row), weight zeroed.
// Pre-committed read: improvement => latency-bound confirmed; null => random-
// gather L3->L2 path is the ceiling, aggf done.

#define QB(v, k) __builtin_amdgcn_ds_swizzle((v), 0x8000 | ((k) * 0x55))

template<int ACT>
__global__ void k_aggf(const unsigned short* __restrict__ h, const float* __restrict__ s,
                       const float* __restrict__ dsc, const int* __restrict__ offs,
                       const int* __restrict__ adj, const float* __restrict__ bias,
                       unsigned short* __restrict__ out16, float* __restrict__ out32,
                       int N, int H) {
    const int C8 = 4;
    long tid = (long)blockIdx.x * blockDim.x + threadIdx.x;
    int HC8 = H * C8;
    if (tid >= (long)N * HC8) return;
    int c8 = (int)(tid % C8);
    int hh = (int)((tid / C8) % H);
    int n  = (int)(tid / HC8);
    int beg = offs[n], end = offs[n + 1];
    float dn = dsc[n * H + hh];
    int HC = HC8 * 8;
    int coff = hh * 32 + c8 * 8;
    const unsigned short* hb = h + coff;

    float denom = 0.f;
    float acc[8];
#pragma unroll
    for (int u = 0; u < 8; ++u) acc[u] = 0.f;

    for (int j = beg; j < end; j += 8) {
        int my0 = j + c8;
        int my1 = my0 + 4;
        int i0 = my0 < end ? my0 : end - 1;
        int i1 = my1 < end ? my1 : end - 1;
        // two coalesced index loads per lane (quad covers j..j+7)
        int p = adj[i0];
        int qn = adj[i1];
        // all 8 sn broadcasts, then all 8 h-gathers in flight together
        int a0 = QB(p, 0), a1 = QB(p, 1), a2 = QB(p, 2), a3 = QB(p, 3);
        int b0 = QB(qn, 0), b1 = QB(qn, 1), b2 = QB(qn, 2), b3 = QB(qn, 3);
        short8 h0 = *(const short8*)(hb + (size_t)a0 * HC);
        short8 h1 = *(const short8*)(hb + (size_t)a1 * HC);
        short8 h2 = *(const short8*)(hb + (size_t)a2 * HC);
        short8 h3 = *(const short8*)(hb + (size_t)a3 * HC);
        short8 h4 = *(const short8*)(hb + (size_t)b0 * HC);
        short8 h5 = *(const short8*)(hb + (size_t)b1 * HC);
        short8 h6 = *(const short8*)(hb + (size_t)b2 * HC);
        short8 h7 = *(const short8*)(hb + (size_t)b3 * HC);
        // scores (overlap with gather latency)
        float e0 = s[p * H + hh] + dn;
        float e1 = s[qn * H + hh] + dn;
        e0 = e0 > 0.f ? e0 : LRELU_SLOPE * e0;
        e1 = e1 > 0.f ? e1 : LRELU_SLOPE * e1;
        float wA = __expf(fminf(e0, 80.f));
        float wB = __expf(fminf(e1, 80.f));
        if (my0 >= end) wA = 0.f;
        if (my1 >= end) wB = 0.f;
        int wiA = __builtin_bit_cast(int, wA);
        int wiB = __builtin_bit_cast(int, wB);
        float w0 = __builtin_bit_cast(float, QB(wiA, 0));
        float w1 = __builtin_bit_cast(float, QB(wiA, 1));
        float w2 = __builtin_bit_cast(float, QB(wiA, 2));
        float w3 = __builtin_bit_cast(float, QB(wiA, 3));
        float w4 = __builtin_bit_cast(float, QB(wiB, 0));
        float w5 = __builtin_bit_cast(float, QB(wiB, 1));
        float w6 = __builtin_bit_cast(float, QB(wiB, 2));
        float w7 = __builtin_bit_cast(float, QB(wiB, 3));
        denom += ((w0 + w1) + (w2 + w3)) + ((w4 + w5) + (w6 + w7));
#pragma unroll
        for (int u = 0; u < 8; ++u) {
            float aa = w0 * bf2f((unsigned short)h0[u]) + w1 * bf2f((unsigned short)h1[u]);
            float ab = w2 * bf2f((unsigned short)h2[u]) + w3 * bf2f((unsigned short)h3[u]);
            float ac = w4 * bf2f((unsigned short)h4[u]) + w5 * bf2f((unsigned short)h5[u]);
            float ad = w6 * bf2f((unsigned short)h6[u]) + w7 * bf2f((unsigned short)h7[u]);
            acc[u] += (aa + ab) + (ac + ad);
        }
    }

    float inv = 1.0f / denom;
    float o[8];
#pragma unroll
    for (int u = 0; u < 8; ++u) o[u] = acc[u] * inv + bias[coff + u];

    if (ACT == 1) {
        short8 pk;
#pragma unroll
        for (int u = 0; u < 8; ++u) {
            float v = o[u] > 0.f ? o[u] : (__expf(o[u]) - 1.f);
            pk[u] = (short)bf16r(v);
        }
        *(short8*)(out16 + tid * 8) = pk;
    } else {
        float m = o[0];
#pragma unroll
        for (int u = 1; u < 8; ++u) m = fmaxf(m, o[u]);
        m = fmaxf(m, __shfl_xor(m, 1));
        m = fmaxf(m, __shfl_xor(m, 2));
        float ssum = 0.f;
#pragma unroll
        for (int u = 0; u < 8; ++u) ssum += __expf(o[u] - m);
        ssum += __shfl_xor(ssum, 1);
        ssum += __shfl_xor(ssum, 2);
        float lse = m + __logf(ssum);
        float4 lo = {o[0] - lse, o[1] - lse, o[2] - lse, o[3] - lse};
        float4 hi = {o[4] - lse, o[5] - lse, o[6] - lse, o[7] - lse};
        *(float4*)(out32 + tid * 8)     = lo;
        *(float4*)(out32 + tid * 8 + 4) = hi;
    }
}

// ---------------- host ----------------

static inline size_t align_up(size_t x) { return (x + 255) & ~(size_t)255; }

extern "C" void kernel_launch(void* const* d_in, const int* in_sizes, int n_in,
                              void* d_out, int out_size, void* d_ws, size_t ws_size,
                              hipStream_t stream) {
    const float* x   = (const float*)d_in[0];
    const int*   ei  = (const int*)d_in[1];

    const int N = in_sizes[0] / 256;   // 50000
    const int E = in_sizes[1] / 2;     // 400000
    const int ET = E + N;
    const int NB = (N + 1023) / 1024;
    const int XC = N * 32;             // x->bf16 conversion threads (8 elems each)

    size_t off = 0;
    char* ws = (char*)d_ws;
    auto take = [&](size_t bytes) { char* p = ws + off; off += align_up(bytes); return p; };
    int*   offs  = (int*)take((size_t)(N + 1) * 4);
    int*   wp    = (int*)take((size_t)N * 4);
    int*   adj   = (int*)take((size_t)ET * 4);
    int*   bsum  = (int*)take((size_t)(NB + 1) * 4);
    int*   bpre  = (int*)take((size_t)(NB + 1) * 4);
    float* sbuf  = (float*)take((size_t)N * 8 * 4);
    float* dbuf  = (float*)take((size_t)N * 8 * 4);
    unsigned short* Xb = (unsigned short*)take((size_t)N * 256 * 2);  // activations (bf16)
    unsigned short* Yb = (unsigned short*)take((size_t)N * 256 * 2);  // h (GEMM out, bf16)
    unsigned short* WT0 = (unsigned short*)take((size_t)256 * 256 * 2);
    unsigned short* WT1 = (unsigned short*)take((size_t)256 * 128 * 2);
    unsigned short* WT2 = (unsigned short*)take((size_t)128 * 64 * 2);
    unsigned short* WT3 = (unsigned short*)take((size_t)64 * 32 * 2);
    (void)ws_size;

    // ---- preamble (x->bf16 + W transpose + edge count) + CSR build ----
    hipMemsetAsync(wp, 0, (size_t)N * 4, stream);
    {
        long tot = (long)XC + WTOT + ET;
        k_pre<<<(int)((tot + 255) / 256), 256, 0, stream>>>(
            x, Xb,
            (const float*)d_in[2], (const float*)d_in[6], (const float*)d_in[10],
            (const float*)d_in[14], WT0, WT1, WT2, WT3, ei, wp, XC, E, N);
        k_scan_blk<<<NB, 1024, 0, stream>>>(wp, offs, bsum, N);
        k_scan<<<1, 1024, 0, stream>>>(bsum, bpre, NB);
        k_scan_add<<<(N + 256) / 256, 256, 0, stream>>>(offs, bpre, wp, N, NB);
        k_scatter<<<(ET + 255) / 256, 256, 0, stream>>>(ei, wp, adj, E, N);
    }

    const float* as_[4] = {(const float*)d_in[3], (const float*)d_in[7],
                           (const float*)d_in[11], (const float*)d_in[15]};
    const float* ad_[4] = {(const float*)d_in[4], (const float*)d_in[8],
                           (const float*)d_in[12], (const float*)d_in[16]};
    const float* b_[4]  = {(const float*)d_in[5], (const float*)d_in[9],
                           (const float*)d_in[13], (const float*)d_in[17]};
    int H_[4] = {8, 4, 2, 1};

    const int RB  = (N + 63) / 64;         // row blocks (782)
    const int RBp = ((RB + 7) / 8) * 8;    // padded to 8 for swizzle (784)

    for (int li = 0; li < 4; ++li) {
        int H = H_[li];

        // GEMM + fused s/d (DMA-staged A/B)
        if (li == 0) {
            k_mgemm<64, 256, 4><<<4 * RBp, 256, 0, stream>>>(
                Xb, WT0, Yb, as_[0], ad_[0], sbuf, dbuf, N, 256, H, RB);
        } else if (li == 1) {
            k_mgemm<64, 256, 2><<<2 * RBp, 256, 0, stream>>>(
                Xb, WT1, Yb, as_[1], ad_[1], sbuf, dbuf, N, 128, H, RB);
        } else if (li == 2) {
            k_mgemm<64, 128, 1><<<RBp, 256, 0, stream>>>(
                Xb, WT2, Yb, as_[2], ad_[2], sbuf, dbuf, N, 64, H, RB);
        } else {
            k_mgemm<32, 64, 1><<<RBp, 256, 0, stream>>>(
                Xb, WT3, Yb, as_[3], ad_[3], sbuf, dbuf, N, 32, H, RB);
        }
        // aggregate (+elu->bf16 for layers 0-2; +log_softmax->d_out for layer 3)
        {
            long total = (long)N * H * 4;
            int nb = (int)((total + 255) / 256);
            if (li < 3)
                k_aggf<1><<<nb, 256, 0, stream>>>(Yb, sbuf, dbuf, offs, adj, b_[li],
                                                  Xb, nullptr, N, H);
            else
                k_aggf<0><<<nb, 256, 0, stream>>>(Yb, sbuf, dbuf, offs, adj, b_[li],
                                                  nullptr, (float*)d_out, N, H);
        }
    }
}

// Round 5
// 308.539 us; speedup vs baseline: 1.0529x; 1.0529x over previous
//
#include <hip/hip_runtime.h>
#include <hip/hip_bf16.h>

#define LRELU_SLOPE 0.2f

typedef __attribute__((ext_vector_type(8))) short short8;
typedef __attribute__((ext_vector_type(4))) float f32x4;

__device__ __forceinline__ unsigned short bf16r(float f) {
    unsigned int u = __builtin_bit_cast(unsigned int, f);
    u += 0x7fffu + ((u >> 16) & 1u);   // RNE
    return (unsigned short)(u >> 16);
}
__device__ __forceinline__ float bf2f(unsigned short u) {
    return __builtin_bit_cast(float, (unsigned int)u << 16);
}

// async global->LDS 16B DMA (guide §5: compiler never auto-emits this)
#define GLD16(g, l)                                                            \
    __builtin_amdgcn_global_load_lds(                                          \
        (const __attribute__((address_space(1))) void*)(g),                    \
        (__attribute__((address_space(3))) void*)(l), 16, 0, 0)

// ---------------- fused preamble: x->bf16 + W->WT bf16 transposed + edge count/slot ----------------

#define WTOT 108544  // 65536 + 32768 + 8192 + 2048

__global__ void k_pre(const float* __restrict__ x, unsigned short* __restrict__ Xb,
                      const float* __restrict__ Wa, const float* __restrict__ Wb,
                      const float* __restrict__ Wc, const float* __restrict__ Wd,
                      unsigned short* __restrict__ Ta, unsigned short* __restrict__ Tb,
                      unsigned short* __restrict__ Tc, unsigned short* __restrict__ Td,
                      const int* __restrict__ ei, int* __restrict__ cnt,
                      int* __restrict__ slot, int XC, int E) {
    int gid = blockIdx.x * blockDim.x + threadIdx.x;
    if (gid < XC) {
        // convert 8 f32 -> 8 bf16 (coalesced float4 x2 -> short8)
        const float4* xp = (const float4*)x + (long)gid * 2;
        float4 a = xp[0], b = xp[1];
        short8 pk;
        pk[0] = (short)bf16r(a.x); pk[1] = (short)bf16r(a.y);
        pk[2] = (short)bf16r(a.z); pk[3] = (short)bf16r(a.w);
        pk[4] = (short)bf16r(b.x); pk[5] = (short)bf16r(b.y);
        pk[6] = (short)bf16r(b.z); pk[7] = (short)bf16r(b.w);
        *(short8*)(Xb + (long)gid * 8) = pk;
        return;
    }
    int id = gid - XC;
    if (id < WTOT) {
        const float* W; unsigned short* T; int K, Nc;
        if (id < 65536)       { W = Wa; T = Ta; K = 256; Nc = 256; }
        else if (id < 98304)  { id -= 65536;  W = Wb; T = Tb; K = 256; Nc = 128; }
        else if (id < 106496) { id -= 98304;  W = Wc; T = Tc; K = 128; Nc = 64; }
        else                  { id -= 106496; W = Wd; T = Td; K = 64;  Nc = 32; }
        int n = id / K, k = id % K;
        T[id] = bf16r(W[(long)k * Nc + n]);
        return;
    }
    int e = id - WTOT;
    if (e >= E) return;
    int dst = ei[E + e];
    slot[e] = atomicAdd(&cnt[dst], 1);   // per-dst slot -> atomic-free scatter later
}

// ---------------- CSR: block scan + (last block) top-level scan in ONE kernel ----------------
// v = cnt[n] + 1 (self-loop reserved at segment head).

__global__ void k_scan_blk(const int* __restrict__ cnt, int* __restrict__ offs,
                           int* __restrict__ bsum, int* __restrict__ bpre,
                           int* __restrict__ done, int N, int NB) {
    __shared__ int temp[1024];
    __shared__ int last_s;
    int t = threadIdx.x;
    int gi = blockIdx.x * 1024 + t;
    int v = (gi < N) ? cnt[gi] + 1 : 0;
    temp[t] = v;
    __syncthreads();
    for (int o = 1; o < 1024; o <<= 1) {
        int x = (t >= o) ? temp[t - o] : 0;
        __syncthreads();
        temp[t] += x;
        __syncthreads();
    }
    if (gi < N) offs[gi] = temp[t] - v;
    if (t == 1023) bsum[blockIdx.x] = temp[1023];
    // last-done block scans bsum -> bpre (scheduling-order safe: no spin)
    if (t == 0) {
        __threadfence();
        last_s = (atomicAdd(done, 1) == NB - 1) ? 1 : 0;
    }
    __syncthreads();
    if (last_s) {
        __threadfence();   // acquire: see all blocks' bsum
        int v2 = (t < NB) ? bsum[t] : 0;
        temp[t] = v2;
        __syncthreads();
        for (int o = 1; o < 1024; o <<= 1) {
            int x = (t >= o) ? temp[t - o] : 0;
            __syncthreads();
            temp[t] += x;
            __syncthreads();
        }
        if (t < NB) bpre[t] = temp[t] - v2;
        if (t == NB - 1) bpre[NB] = temp[t];
    }
}

__global__ void k_scan_add(int* __restrict__ offs, const int* __restrict__ bpre,
                           int* __restrict__ adj, int N, int nb) {
    int gi = blockIdx.x * blockDim.x + threadIdx.x;
    if (gi < N) {
        int v = offs[gi] + bpre[gi >> 10];
        offs[gi] = v;
        adj[v] = gi;           // self-loop at segment head
    } else if (gi == N) {
        offs[N] = bpre[nb];
    }
}

__global__ void k_scatter(const int* __restrict__ ei, const int* __restrict__ offs,
                          const int* __restrict__ slot, int* __restrict__ adj, int E) {
    int e = blockIdx.x * blockDim.x + threadIdx.x;
    if (e >= E) return;
    int srcn = ei[e];
    int dst  = ei[E + e];
    adj[offs[dst] + 1 + slot[e]] = srcn;   // no atomics
}

// ---------------- MFMA GEMM + fused s/d scores ----------------
// r14: A AND B staged via global_load_lds width-16 (linear LDS dest, pre-swizzled
// global source; XOR-swizzled ds_read_b128 frag reads). KT == full K, so tiles
// are contiguous in global -> perfectly coalesced DMA. This removed k_mgemm from
// the top-5 (was 46.5us at 29% occupancy with per-lane register prefetch).

template<int BN, int KT, int GX>
__global__ __launch_bounds__(256) void k_mgemm(const unsigned short* __restrict__ Ab,
                                               const unsigned short* __restrict__ WT,
                                               unsigned short* __restrict__ Cb,
                                               const float* __restrict__ a_src,
                                               const float* __restrict__ a_dst,
                                               float* __restrict__ sbuf,
                                               float* __restrict__ dbuf,
                                               int M, int Nc, int H, int RB) {
    constexpr int KITER = KT / 32;        // K-steps (also A-stage iters)
    constexpr int NBF = BN / 16;          // B fragments per wave
    constexpr int CPR = BN / 32;          // 32-col chunks per row (epilogue)
    constexpr int SP  = BN + 8;           // epilogue LDS row stride
    constexpr int ASH = 64 * KT;          // A shorts
    constexpr int BSH = BN * KT;          // B shorts
    constexpr int EPIL = 64 * SP;
    constexpr int LBSZ = (ASH + BSH) > EPIL ? (ASH + BSH) : EPIL;
    constexpr int SHC = (KT == 256) ? 5 : (KT == 128 ? 4 : 3);  // log2(chunks per row)
    constexpr int BIT = BN * KT / 2048;   // B-stage iters
    __shared__ __align__(16) unsigned short LB[LBSZ];

    // swizzled decode: id = xcd + 8*( (rb/8)*GX + ct ), rb = (q/GX)*8 + xcd
    int id = blockIdx.x;
    int xcd = id & 7;
    int q  = id >> 3;
    int ct = q % GX;
    int rb = (q / GX) * 8 + xcd;
    if (rb >= RB) return;
    int bm = rb * 64, bn = ct * BN;

    int t = threadIdx.x;
    int wv = t >> 6, l = t & 63;
    int row_in = l & 15, quad = l >> 4;
    char* LBb = (char*)LB;

    // ---- stage A tile (64 x KT bf16, contiguous in global) via DMA ----
    long abyte = (long)bm * (KT * 2);
    long mbyte = (long)M * (KT * 2);
    const char* Agb = (const char*)Ab;
#pragma unroll
    for (int i = 0; i < KITER; ++i) {
        int c = i * 256 + t;
        int cs = c ^ ((c >> SHC) & 7);
        long gb = abyte + (long)cs * 16;
        if (gb >= mbyte) gb = abyte;            // OOB tail rows: garbage, masked at store
        GLD16(Agb + gb, LBb + (i * 256 + wv * 64) * 16);
    }
    // ---- stage B tile (BN x KT bf16, contiguous in WT) via DMA ----
    const char* WTb = (const char*)WT + (long)bn * (KT * 2);
#pragma unroll
    for (int i = 0; i < BIT; ++i) {
        int c = i * 256 + t;
        int cs = c ^ ((c >> SHC) & 7);
        GLD16(WTb + (long)cs * 16, LBb + ASH * 2 + (i * 256 + wv * 64) * 16);
    }
    asm volatile("s_waitcnt vmcnt(0)" ::: "memory");
    __syncthreads();

    f32x4 acc[NBF];
#pragma unroll
    for (int j = 0; j < NBF; ++j) acc[j] = (f32x4){0.f, 0.f, 0.f, 0.f};

    // ---- K loop: pure LDS -> MFMA, swizzled b128 reads ----
    int arow = wv * 16 + row_in;
#pragma unroll
    for (int ki = 0; ki < KITER; ++ki) {
        int aoff = (arow * (KT * 2) + ki * 64 + quad * 16) ^ ((arow & 7) << 4);
        short8 av = *(const short8*)(LBb + aoff);
#pragma unroll
        for (int f = 0; f < NBF; ++f) {
            int bcol = f * 16 + row_in;
            int boff = ASH * 2 + ((bcol * (KT * 2) + ki * 64 + quad * 16) ^ ((bcol & 7) << 4));
            short8 bv = *(const short8*)(LBb + boff);
            acc[f] = __builtin_amdgcn_mfma_f32_16x16x32_bf16(av, bv, acc[f], 0, 0, 0);
        }
    }
    __syncthreads();   // before LDS reuse for epilogue

    // ---- epilogue: LDS repack (bf16) -> coalesced stores + fused s/d ----
#pragma unroll
    for (int r = 0; r < 4; ++r)
#pragma unroll
        for (int f = 0; f < NBF; ++f)
            LB[(wv * 16 + quad * 4 + r) * SP + f * 16 + row_in] = bf16r(acc[f][r]);
    __syncthreads();

    int rr = t / CPR, cc = t % CPR;
    if (rr < 64) {
        int grow = bm + rr;
        int colb = bn + cc * 32;
        if (grow < M && colb < Nc) {
            const unsigned short* ep = &LB[rr * SP + cc * 32];
            short8 v0 = *(const short8*)(ep);
            short8 v1 = *(const short8*)(ep + 8);
            short8 v2 = *(const short8*)(ep + 16);
            short8 v3 = *(const short8*)(ep + 24);
            unsigned short* cp = &Cb[(long)grow * Nc + colb];
            *(short8*)(cp)      = v0;
            *(short8*)(cp + 8)  = v1;
            *(short8*)(cp + 16) = v2;
            *(short8*)(cp + 24) = v3;
            int hd = colb >> 5;   // 32 channels per head
            const float* ap = a_src + hd * 32;
            const float* dp = a_dst + hd * 32;
            float ss = 0.f, dd = 0.f;
#pragma unroll
            for (int u = 0; u < 8; ++u) {
                float va = bf2f((unsigned short)v0[u]); ss += va * ap[u];      dd += va * dp[u];
                float vb = bf2f((unsigned short)v1[u]); ss += vb * ap[8 + u];  dd += vb * dp[8 + u];
                float vc = bf2f((unsigned short)v2[u]); ss += vc * ap[16 + u]; dd += vc * dp[16 + u];
                float vd = bf2f((unsigned short)v3[u]); ss += vd * ap[24 + u]; dd += vd * dp[24 + u];
            }
            sbuf[(long)grow * H + hd] = ss;
            dbuf[(long)grow * H + hd] = dd;
        }
    }
}

// ---------------- fused aggregate: max-free softmax, single pass ----------------
// r13 4-wide quad-coop (measured best: 44.2us L0, occ 63%). Each lane of a quad
// owns one edge (coalesced adj load, 1 s-gather, 1 exp), quad-broadcast via
// ds_swizzle. 8-wide (r15) was null->regression: random-gather L2-miss path
// (~119MB @ ~3 TB/s for 512B-granule random) is the ceiling for this kernel.

#define QB(v, k) __builtin_amdgcn_ds_swizzle((v), 0x8000 | ((k) * 0x55))

template<int ACT>
__global__ void k_aggf(const unsigned short* __restrict__ h, const float* __restrict__ s,
                       const float* __restrict__ dsc, const int* __restrict__ offs,
                       const int* __restrict__ adj, const float* __restrict__ bias,
                       unsigned short* __restrict__ out16, float* __restrict__ out32,
                       int N, int H) {
    const int C8 = 4;
    long tid = (long)blockIdx.x * blockDim.x + threadIdx.x;
    int HC8 = H * C8;
    if (tid >= (long)N * HC8) return;
    int c8 = (int)(tid % C8);
    int hh = (int)((tid / C8) % H);
    int n  = (int)(tid / HC8);
    int beg = offs[n], end = offs[n + 1];
    float dn = dsc[n * H + hh];
    int HC = HC8 * 8;
    int coff = hh * 32 + c8 * 8;
    const unsigned short* hb = h + coff;

    float denom = 0.f;
    float acc[8];
#pragma unroll
    for (int u = 0; u < 8; ++u) acc[u] = 0.f;

    for (int j = beg; j < end; j += 4) {
        int my = j + c8;
        int idx = my < end ? my : end - 1;
        int sn = adj[idx];                       // coalesced: quad reads j..j+3
        float e = s[sn * H + hh] + dn;           // one scattered 4B gather per lane
        e = e > 0.f ? e : LRELU_SLOPE * e;
        float w = __expf(fminf(e, 80.f));        // one exp per lane
        if (my >= end) w = 0.f;                  // mask tail
        int wi = __builtin_bit_cast(int, w);
        int sn0 = QB(sn, 0);
        int sn1 = QB(sn, 1);
        int sn2 = QB(sn, 2);
        int sn3 = QB(sn, 3);
        float w0 = __builtin_bit_cast(float, QB(wi, 0));
        float w1 = __builtin_bit_cast(float, QB(wi, 1));
        float w2 = __builtin_bit_cast(float, QB(wi, 2));
        float w3 = __builtin_bit_cast(float, QB(wi, 3));
        short8 h0 = *(const short8*)(hb + (size_t)sn0 * HC);
        short8 h1 = *(const short8*)(hb + (size_t)sn1 * HC);
        short8 h2 = *(const short8*)(hb + (size_t)sn2 * HC);
        short8 h3 = *(const short8*)(hb + (size_t)sn3 * HC);
        denom += (w0 + w1) + (w2 + w3);
#pragma unroll
        for (int u = 0; u < 8; ++u) {
            float a01 = w0 * bf2f((unsigned short)h0[u]) + w1 * bf2f((unsigned short)h1[u]);
            float a23 = w2 * bf2f((unsigned short)h2[u]) + w3 * bf2f((unsigned short)h3[u]);
            acc[u] += a01 + a23;
        }
    }

    float inv = 1.0f / denom;
    float o[8];
#pragma unroll
    for (int u = 0; u < 8; ++u) o[u] = acc[u] * inv + bias[coff + u];

    if (ACT == 1) {
        short8 pk;
#pragma unroll
        for (int u = 0; u < 8; ++u) {
            float v = o[u] > 0.f ? o[u] : (__expf(o[u]) - 1.f);
            pk[u] = (short)bf16r(v);
        }
        *(short8*)(out16 + tid * 8) = pk;
    } else {
        float m = o[0];
#pragma unroll
        for (int u = 1; u < 8; ++u) m = fmaxf(m, o[u]);
        m = fmaxf(m, __shfl_xor(m, 1));
        m = fmaxf(m, __shfl_xor(m, 2));
        float ssum = 0.f;
#pragma unroll
        for (int u = 0; u < 8; ++u) ssum += __expf(o[u] - m);
        ssum += __shfl_xor(ssum, 1);
        ssum += __shfl_xor(ssum, 2);
        float lse = m + __logf(ssum);
        float4 lo = {o[0] - lse, o[1] - lse, o[2] - lse, o[3] - lse};
        float4 hi = {o[4] - lse, o[5] - lse, o[6] - lse, o[7] - lse};
        *(float4*)(out32 + tid * 8)     = lo;
        *(float4*)(out32 + tid * 8 + 4) = hi;
    }
}

// ---------------- host ----------------

static inline size_t align_up(size_t x) { return (x + 255) & ~(size_t)255; }

extern "C" void kernel_launch(void* const* d_in, const int* in_sizes, int n_in,
                              void* d_out, int out_size, void* d_ws, size_t ws_size,
                              hipStream_t stream) {
    const float* x   = (const float*)d_in[0];
    const int*   ei  = (const int*)d_in[1];

    const int N = in_sizes[0] / 256;   // 50000
    const int E = in_sizes[1] / 2;     // 400000
    const int ET = E + N;
    const int NB = (N + 1023) / 1024;
    const int XC = N * 32;             // x->bf16 conversion threads (8 elems each)

    size_t off = 0;
    char* ws = (char*)d_ws;
    auto take = [&](size_t bytes) { char* p = ws + off; off += align_up(bytes); return p; };
    int*   offs  = (int*)take((size_t)(N + 1) * 4);
    int*   cntd  = (int*)take((size_t)(N + 1) * 4);   // cnt[N] + done flag
    int*   slot  = (int*)take((size_t)E * 4);
    int*   adj   = (int*)take((size_t)ET * 4);
    int*   bsum  = (int*)take((size_t)(NB + 1) * 4);
    int*   bpre  = (int*)take((size_t)(NB + 1) * 4);
    float* sbuf  = (float*)take((size_t)N * 8 * 4);
    float* dbuf  = (float*)take((size_t)N * 8 * 4);
    unsigned short* Xb = (unsigned short*)take((size_t)N * 256 * 2);  // activations (bf16)
    unsigned short* Yb = (unsigned short*)take((size_t)N * 256 * 2);  // h (GEMM out, bf16)
    unsigned short* WT0 = (unsigned short*)take((size_t)256 * 256 * 2);
    unsigned short* WT1 = (unsigned short*)take((size_t)256 * 128 * 2);
    unsigned short* WT2 = (unsigned short*)take((size_t)128 * 64 * 2);
    unsigned short* WT3 = (unsigned short*)take((size_t)64 * 32 * 2);
    (void)ws_size;

    int* cnt  = cntd;
    int* done = cntd + N;

    // ---- preamble (x->bf16 + W transpose + edge count/slot) + CSR build ----
    hipMemsetAsync(cntd, 0, (size_t)(N + 1) * 4, stream);
    {
        long tot = (long)XC + WTOT + E;
        k_pre<<<(int)((tot + 255) / 256), 256, 0, stream>>>(
            x, Xb,
            (const float*)d_in[2], (const float*)d_in[6], (const float*)d_in[10],
            (const float*)d_in[14], WT0, WT1, WT2, WT3, ei, cnt, slot, XC, E);
        k_scan_blk<<<NB, 1024, 0, stream>>>(cnt, offs, bsum, bpre, done, N, NB);
        k_scan_add<<<(N + 256) / 256, 256, 0, stream>>>(offs, bpre, adj, N, NB);
        k_scatter<<<(E + 255) / 256, 256, 0, stream>>>(ei, offs, slot, adj, E);
    }

    const float* as_[4] = {(const float*)d_in[3], (const float*)d_in[7],
                           (const float*)d_in[11], (const float*)d_in[15]};
    const float* ad_[4] = {(const float*)d_in[4], (const float*)d_in[8],
                           (const float*)d_in[12], (const float*)d_in[16]};
    const float* b_[4]  = {(const float*)d_in[5], (const float*)d_in[9],
                           (const float*)d_in[13], (const float*)d_in[17]};
    int H_[4] = {8, 4, 2, 1};

    const int RB  = (N + 63) / 64;         // row blocks (782)
    const int RBp = ((RB + 7) / 8) * 8;    // padded to 8 for swizzle (784)

    for (int li = 0; li < 4; ++li) {
        int H = H_[li];

        // GEMM + fused s/d (DMA-staged A/B)
        if (li == 0) {
            k_mgemm<64, 256, 4><<<4 * RBp, 256, 0, stream>>>(
                Xb, WT0, Yb, as_[0], ad_[0], sbuf, dbuf, N, 256, H, RB);
        } else if (li == 1) {
            k_mgemm<64, 256, 2><<<2 * RBp, 256, 0, stream>>>(
                Xb, WT1, Yb, as_[1], ad_[1], sbuf, dbuf, N, 128, H, RB);
        } else if (li == 2) {
            k_mgemm<64, 128, 1><<<RBp, 256, 0, stream>>>(
                Xb, WT2, Yb, as_[2], ad_[2], sbuf, dbuf, N, 64, H, RB);
        } else {
            k_mgemm<32, 64, 1><<<RBp, 256, 0, stream>>>(
                Xb, WT3, Yb, as_[3], ad_[3], sbuf, dbuf, N, 32, H, RB);
        }
        // aggregate (+elu->bf16 for layers 0-2; +log_softmax->d_out for layer 3)
        {
            long total = (long)N * H * 4;
            int nb = (int)((total + 255) / 256);
            if (li < 3)
                k_aggf<1><<<nb, 256, 0, stream>>>(Yb, sbuf, dbuf, offs, adj, b_[li],
                                                  Xb, nullptr, N, H);
            else
                k_aggf<0><<<nb, 256, 0, stream>>>(Yb, sbuf, dbuf, offs, adj, b_[li],
                                                  nullptr, (float*)d_out, N, H);
        }
    }
}

// Round 6
// 294.750 us; speedup vs baseline: 1.1021x; 1.0468x over previous
//
#include <hip/hip_runtime.h>
#include <hip/hip_bf16.h>

#define LRELU_SLOPE 0.2f

typedef __attribute__((ext_vector_type(8))) short short8;
typedef __attribute__((ext_vector_type(4))) float f32x4;

__device__ __forceinline__ unsigned short bf16r(float f) {
    unsigned int u = __builtin_bit_cast(unsigned int, f);
    u += 0x7fffu + ((u >> 16) & 1u);   // RNE
    return (unsigned short)(u >> 16);
}
__device__ __forceinline__ float bf2f(unsigned short u) {
    return __builtin_bit_cast(float, (unsigned int)u << 16);
}

// async global->LDS 16B DMA (guide §5: compiler never auto-emits this)
#define GLD16(g, l)                                                            \
    __builtin_amdgcn_global_load_lds(                                          \
        (const __attribute__((address_space(1))) void*)(g),                    \
        (__attribute__((address_space(3))) void*)(l), 16, 0, 0)

// ---------------- fused preamble: x->bf16 + W->WT bf16 transposed + edge count/slot ----------------

#define WTOT 108544  // 65536 + 32768 + 8192 + 2048

__global__ void k_pre(const float* __restrict__ x, unsigned short* __restrict__ Xb,
                      const float* __restrict__ Wa, const float* __restrict__ Wb,
                      const float* __restrict__ Wc, const float* __restrict__ Wd,
                      unsigned short* __restrict__ Ta, unsigned short* __restrict__ Tb,
                      unsigned short* __restrict__ Tc, unsigned short* __restrict__ Td,
                      const int* __restrict__ ei, int* __restrict__ cnt,
                      int* __restrict__ slot, int XC, int E) {
    int gid = blockIdx.x * blockDim.x + threadIdx.x;
    if (gid < XC) {
        // convert 8 f32 -> 8 bf16 (coalesced float4 x2 -> short8)
        const float4* xp = (const float4*)x + (long)gid * 2;
        float4 a = xp[0], b = xp[1];
        short8 pk;
        pk[0] = (short)bf16r(a.x); pk[1] = (short)bf16r(a.y);
        pk[2] = (short)bf16r(a.z); pk[3] = (short)bf16r(a.w);
        pk[4] = (short)bf16r(b.x); pk[5] = (short)bf16r(b.y);
        pk[6] = (short)bf16r(b.z); pk[7] = (short)bf16r(b.w);
        *(short8*)(Xb + (long)gid * 8) = pk;
        return;
    }
    int id = gid - XC;
    if (id < WTOT) {
        const float* W; unsigned short* T; int K, Nc;
        if (id < 65536)       { W = Wa; T = Ta; K = 256; Nc = 256; }
        else if (id < 98304)  { id -= 65536;  W = Wb; T = Tb; K = 256; Nc = 128; }
        else if (id < 106496) { id -= 98304;  W = Wc; T = Tc; K = 128; Nc = 64; }
        else                  { id -= 106496; W = Wd; T = Td; K = 64;  Nc = 32; }
        int n = id / K, k = id % K;
        T[id] = bf16r(W[(long)k * Nc + n]);
        return;
    }
    int e = id - WTOT;
    if (e >= E) return;
    int dst = ei[E + e];
    slot[e] = atomicAdd(&cnt[dst], 1);   // per-dst slot -> atomic-free scatter later
}

// ---------------- CSR: block scan + (last block) top-level scan in ONE kernel ----------------
// v = cnt[n] + 1 (self-loop reserved at segment head). Writes RAW offs (offsR).

__global__ void k_scan_blk(const int* __restrict__ cnt, int* __restrict__ offsR,
                           int* __restrict__ bsum, int* __restrict__ bpre,
                           int* __restrict__ done, int N, int NB) {
    __shared__ int temp[1024];
    __shared__ int last_s;
    int t = threadIdx.x;
    int gi = blockIdx.x * 1024 + t;
    int v = (gi < N) ? cnt[gi] + 1 : 0;
    temp[t] = v;
    __syncthreads();
    for (int o = 1; o < 1024; o <<= 1) {
        int x = (t >= o) ? temp[t - o] : 0;
        __syncthreads();
        temp[t] += x;
        __syncthreads();
    }
    if (gi < N) offsR[gi] = temp[t] - v;
    if (t == 1023) bsum[blockIdx.x] = temp[1023];
    // last-done block scans bsum -> bpre (scheduling-order safe: no spin)
    if (t == 0) {
        __threadfence();
        last_s = (atomicAdd(done, 1) == NB - 1) ? 1 : 0;
    }
    __syncthreads();
    if (last_s) {
        __threadfence();   // acquire: see all blocks' bsum
        int v2 = (t < NB) ? bsum[t] : 0;
        temp[t] = v2;
        __syncthreads();
        for (int o = 1; o < 1024; o <<= 1) {
            int x = (t >= o) ? temp[t - o] : 0;
            __syncthreads();
            temp[t] += x;
            __syncthreads();
        }
        if (t < NB) bpre[t] = temp[t] - v2;
        if (t == NB - 1) bpre[NB] = temp[t];
    }
}

// ---------------- finalize offs + self-loops + scatter, ONE kernel ----------------
// Edge part reads only offsR (raw) + bpre -> no race with the offs finalization.

__global__ void k_finalize(const int* __restrict__ ei, const int* __restrict__ offsR,
                           const int* __restrict__ bpre, const int* __restrict__ slot,
                           int* __restrict__ offs, int* __restrict__ adj,
                           int N, int NB, int E) {
    int gi = blockIdx.x * blockDim.x + threadIdx.x;
    int NA = (N + 256) & ~255;
    if (gi < NA) {
        if (gi < N) {
            int v = offsR[gi] + bpre[gi >> 10];
            offs[gi] = v;
            adj[v] = gi;                       // self-loop at segment head
        } else if (gi == N) {
            offs[N] = bpre[NB];
        }
        return;
    }
    int e = gi - NA;
    if (e >= E) return;
    int srcn = ei[e];
    int dst  = ei[E + e];
    adj[offsR[dst] + bpre[dst >> 10] + 1 + slot[e]] = srcn;   // no atomics
}

// ---------------- MFMA GEMM + fused s/d scores ----------------
// r16: K-SPLIT staging. Full-K staging used 64KB LDS -> 2 blocks/CU; each block's
// vmcnt(0)+barrier drain left the CU ~idle (mgemm L0/L1 ~40us hiding under the
// top-5 cutoff). Staging K in KH=128 halves halves LDS to 32KB -> 5 blocks/CU,
// cross-block overlap hides the drain. Same DMA bytes; acc carried across rounds.
// Swizzle (both-sides): source chunk-in-row ci^(row&7), read byte ^ (row&7)<<4.

template<int BN, int KT, int GX>
__global__ __launch_bounds__(256) void k_mgemm(const unsigned short* __restrict__ Ab,
                                               const unsigned short* __restrict__ WT,
                                               unsigned short* __restrict__ Cb,
                                               const float* __restrict__ a_src,
                                               const float* __restrict__ a_dst,
                                               float* __restrict__ sbuf,
                                               float* __restrict__ dbuf,
                                               int M, int Nc, int H, int RB) {
    constexpr int KH   = (KT == 256) ? 128 : KT;  // staged K-half
    constexpr int NR   = KT / KH;                 // staging rounds (2 or 1)
    constexpr int KITER = KH / 32;                // K-steps per round
    constexpr int NBF = BN / 16;                  // B fragments per wave
    constexpr int CPR = BN / 32;                  // 32-col chunks per row (epilogue)
    constexpr int SP  = BN + 8;                   // epilogue LDS row stride
    constexpr int ASH = 64 * KH;                  // A shorts staged per round
    constexpr int BSH = BN * KH;                  // B shorts staged per round
    constexpr int EPIL = 64 * SP;
    constexpr int LBSZ = (ASH + BSH) > EPIL ? (ASH + BSH) : EPIL;
    constexpr int CHR = KH / 8;                   // 16B chunks per row (>=8)
    constexpr int SHC = (KH == 128) ? 4 : 3;      // log2(CHR)
    constexpr int AIT = CHR / 4;                  // A-stage iters (64*CHR/256)
    constexpr int BIT = BN * CHR / 256;           // B-stage iters
    __shared__ __align__(16) unsigned short LB[LBSZ];

    // swizzled decode: id = xcd + 8*( (rb/8)*GX + ct ), rb = (q/GX)*8 + xcd
    int id = blockIdx.x;
    int xcd = id & 7;
    int q  = id >> 3;
    int ct = q % GX;
    int rb = (q / GX) * 8 + xcd;
    if (rb >= RB) return;
    int bm = rb * 64, bn = ct * BN;

    int t = threadIdx.x;
    int wv = t >> 6, l = t & 63;
    int row_in = l & 15, quad = l >> 4;
    char* LBb = (char*)LB;

    const char* Agb = (const char*)Ab;
    const char* WTb = (const char*)WT;

    f32x4 acc[NBF];
#pragma unroll
    for (int j = 0; j < NBF; ++j) acc[j] = (f32x4){0.f, 0.f, 0.f, 0.f};

    int arow = wv * 16 + row_in;

#pragma unroll
    for (int r = 0; r < NR; ++r) {
        if (r > 0) __syncthreads();   // all compute on previous half done

        // ---- stage A half-tile (64 x KH bf16) via DMA, pre-swizzled source ----
#pragma unroll
        for (int i = 0; i < AIT; ++i) {
            int c = i * 256 + t;
            int row = c >> SHC;
            int ci  = c & (CHR - 1);
            int cis = ci ^ (row & 7);
            int grow = bm + row; if (grow >= M) grow = M - 1;
            long gb = (long)grow * (KT * 2) + r * (KH * 2) + cis * 16;
            GLD16(Agb + gb, LBb + (i * 256 + wv * 64) * 16);
        }
        // ---- stage B half-tile (BN x KH bf16) via DMA ----
#pragma unroll
        for (int i = 0; i < BIT; ++i) {
            int c = i * 256 + t;
            int col = c >> SHC;
            int ci  = c & (CHR - 1);
            int cis = ci ^ (col & 7);
            long gb = (long)(bn + col) * (KT * 2) + r * (KH * 2) + cis * 16;
            GLD16(WTb + gb, LBb + ASH * 2 + (i * 256 + wv * 64) * 16);
        }
        asm volatile("s_waitcnt vmcnt(0)" ::: "memory");
        __syncthreads();

        // ---- K loop over this half: pure LDS -> MFMA, swizzled b128 reads ----
#pragma unroll
        for (int ki = 0; ki < KITER; ++ki) {
            int aoff = (arow * (KH * 2) + ki * 64 + quad * 16) ^ ((arow & 7) << 4);
            short8 av = *(const short8*)(LBb + aoff);
#pragma unroll
            for (int f = 0; f < NBF; ++f) {
                int bcol = f * 16 + row_in;
                int boff = ASH * 2 + ((bcol * (KH * 2) + ki * 64 + quad * 16) ^ ((bcol & 7) << 4));
                short8 bv = *(const short8*)(LBb + boff);
                acc[f] = __builtin_amdgcn_mfma_f32_16x16x32_bf16(av, bv, acc[f], 0, 0, 0);
            }
        }
    }
    __syncthreads();   // before LDS reuse for epilogue

    // ---- epilogue: LDS repack (bf16) -> coalesced stores + fused s/d ----
#pragma unroll
    for (int r = 0; r < 4; ++r)
#pragma unroll
        for (int f = 0; f < NBF; ++f)
            LB[(wv * 16 + quad * 4 + r) * SP + f * 16 + row_in] = bf16r(acc[f][r]);
    __syncthreads();

    int rr = t / CPR, cc = t % CPR;
    if (rr < 64) {
        int grow = bm + rr;
        int colb = bn + cc * 32;
        if (grow < M && colb < Nc) {
            const unsigned short* ep = &LB[rr * SP + cc * 32];
            short8 v0 = *(const short8*)(ep);
            short8 v1 = *(const short8*)(ep + 8);
            short8 v2 = *(const short8*)(ep + 16);
            short8 v3 = *(const short8*)(ep + 24);
            unsigned short* cp = &Cb[(long)grow * Nc + colb];
            *(short8*)(cp)      = v0;
            *(short8*)(cp + 8)  = v1;
            *(short8*)(cp + 16) = v2;
            *(short8*)(cp + 24) = v3;
            int hd = colb >> 5;   // 32 channels per head
            const float* ap = a_src + hd * 32;
            const float* dp = a_dst + hd * 32;
            float ss = 0.f, dd = 0.f;
#pragma unroll
            for (int u = 0; u < 8; ++u) {
                float va = bf2f((unsigned short)v0[u]); ss += va * ap[u];      dd += va * dp[u];
                float vb = bf2f((unsigned short)v1[u]); ss += vb * ap[8 + u];  dd += vb * dp[8 + u];
                float vc = bf2f((unsigned short)v2[u]); ss += vc * ap[16 + u]; dd += vc * dp[16 + u];
                float vd = bf2f((unsigned short)v3[u]); ss += vd * ap[24 + u]; dd += vd * dp[24 + u];
            }
            sbuf[(long)grow * H + hd] = ss;
            dbuf[(long)grow * H + hd] = dd;
        }
    }
}

// ---------------- fused aggregate: max-free softmax, single pass ----------------
// r13 4-wide quad-coop (measured best: 42us L0, occ 63%). At the random-gather
// L2-miss throughput bound (119MB FETCH, three loop variants identical) -> done.

#define QB(v, k) __builtin_amdgcn_ds_swizzle((v), 0x8000 | ((k) * 0x55))

template<int ACT>
__global__ void k_aggf(const unsigned short* __restrict__ h, const float* __restrict__ s,
                       const float* __restrict__ dsc, const int* __restrict__ offs,
                       const int* __restrict__ adj, const float* __restrict__ bias,
                       unsigned short* __restrict__ out16, float* __restrict__ out32,
                       int N, int H) {
    const int C8 = 4;
    long tid = (long)blockIdx.x * blockDim.x + threadIdx.x;
    int HC8 = H * C8;
    if (tid >= (long)N * HC8) return;
    int c8 = (int)(tid % C8);
    int hh = (int)((tid / C8) % H);
    int n  = (int)(tid / HC8);
    int beg = offs[n], end = offs[n + 1];
    float dn = dsc[n * H + hh];
    int HC = HC8 * 8;
    int coff = hh * 32 + c8 * 8;
    const unsigned short* hb = h + coff;

    float denom = 0.f;
    float acc[8];
#pragma unroll
    for (int u = 0; u < 8; ++u) acc[u] = 0.f;

    for (int j = beg; j < end; j += 4) {
        int my = j + c8;
        int idx = my < end ? my : end - 1;
        int sn = adj[idx];                       // coalesced: quad reads j..j+3
        float e = s[sn * H + hh] + dn;           // one scattered 4B gather per lane
        e = e > 0.f ? e : LRELU_SLOPE * e;
        float w = __expf(fminf(e, 80.f));        // one exp per lane
        if (my >= end) w = 0.f;                  // mask tail
        int wi = __builtin_bit_cast(int, w);
        int sn0 = QB(sn, 0);
        int sn1 = QB(sn, 1);
        int sn2 = QB(sn, 2);
        int sn3 = QB(sn, 3);
        float w0 = __builtin_bit_cast(float, QB(wi, 0));
        float w1 = __builtin_bit_cast(float, QB(wi, 1));
        float w2 = __builtin_bit_cast(float, QB(wi, 2));
        float w3 = __builtin_bit_cast(float, QB(wi, 3));
        short8 h0 = *(const short8*)(hb + (size_t)sn0 * HC);
        short8 h1 = *(const short8*)(hb + (size_t)sn1 * HC);
        short8 h2 = *(const short8*)(hb + (size_t)sn2 * HC);
        short8 h3 = *(const short8*)(hb + (size_t)sn3 * HC);
        denom += (w0 + w1) + (w2 + w3);
#pragma unroll
        for (int u = 0; u < 8; ++u) {
            float a01 = w0 * bf2f((unsigned short)h0[u]) + w1 * bf2f((unsigned short)h1[u]);
            float a23 = w2 * bf2f((unsigned short)h2[u]) + w3 * bf2f((unsigned short)h3[u]);
            acc[u] += a01 + a23;
        }
    }

    float inv = 1.0f / denom;
    float o[8];
#pragma unroll
    for (int u = 0; u < 8; ++u) o[u] = acc[u] * inv + bias[coff + u];

    if (ACT == 1) {
        short8 pk;
#pragma unroll
        for (int u = 0; u < 8; ++u) {
            float v = o[u] > 0.f ? o[u] : (__expf(o[u]) - 1.f);
            pk[u] = (short)bf16r(v);
        }
        *(short8*)(out16 + tid * 8) = pk;
    } else {
        float m = o[0];
#pragma unroll
        for (int u = 1; u < 8; ++u) m = fmaxf(m, o[u]);
        m = fmaxf(m, __shfl_xor(m, 1));
        m = fmaxf(m, __shfl_xor(m, 2));
        float ssum = 0.f;
#pragma unroll
        for (int u = 0; u < 8; ++u) ssum += __expf(o[u] - m);
        ssum += __shfl_xor(ssum, 1);
        ssum += __shfl_xor(ssum, 2);
        float lse = m + __logf(ssum);
        float4 lo = {o[0] - lse, o[1] - lse, o[2] - lse, o[3] - lse};
        float4 hi = {o[4] - lse, o[5] - lse, o[6] - lse, o[7] - lse};
        *(float4*)(out32 + tid * 8)     = lo;
        *(float4*)(out32 + tid * 8 + 4) = hi;
    }
}

// ---------------- host ----------------

static inline size_t align_up(size_t x) { return (x + 255) & ~(size_t)255; }

extern "C" void kernel_launch(void* const* d_in, const int* in_sizes, int n_in,
                              void* d_out, int out_size, void* d_ws, size_t ws_size,
                              hipStream_t stream) {
    const float* x   = (const float*)d_in[0];
    const int*   ei  = (const int*)d_in[1];

    const int N = in_sizes[0] / 256;   // 50000
    const int E = in_sizes[1] / 2;     // 400000
    const int ET = E + N;
    const int NB = (N + 1023) / 1024;
    const int XC = N * 32;             // x->bf16 conversion threads (8 elems each)

    size_t off = 0;
    char* ws = (char*)d_ws;
    auto take = [&](size_t bytes) { char* p = ws + off; off += align_up(bytes); return p; };
    int*   offs  = (int*)take((size_t)(N + 1) * 4);
    int*   offsR = (int*)take((size_t)(N + 1) * 4);
    int*   cntd  = (int*)take((size_t)(N + 1) * 4);   // cnt[N] + done flag
    int*   slot  = (int*)take((size_t)E * 4);
    int*   adj   = (int*)take((size_t)ET * 4);
    int*   bsum  = (int*)take((size_t)(NB + 1) * 4);
    int*   bpre  = (int*)take((size_t)(NB + 1) * 4);
    float* sbuf  = (float*)take((size_t)N * 8 * 4);
    float* dbuf  = (float*)take((size_t)N * 8 * 4);
    unsigned short* Xb = (unsigned short*)take((size_t)N * 256 * 2);  // activations (bf16)
    unsigned short* Yb = (unsigned short*)take((size_t)N * 256 * 2);  // h (GEMM out, bf16)
    unsigned short* WT0 = (unsigned short*)take((size_t)256 * 256 * 2);
    unsigned short* WT1 = (unsigned short*)take((size_t)256 * 128 * 2);
    unsigned short* WT2 = (unsigned short*)take((size_t)128 * 64 * 2);
    unsigned short* WT3 = (unsigned short*)take((size_t)64 * 32 * 2);
    (void)ws_size;

    int* cnt  = cntd;
    int* done = cntd + N;

    // ---- preamble (x->bf16 + W transpose + edge count/slot) + CSR build ----
    hipMemsetAsync(cntd, 0, (size_t)(N + 1) * 4, stream);
    {
        long tot = (long)XC + WTOT + E;
        k_pre<<<(int)((tot + 255) / 256), 256, 0, stream>>>(
            x, Xb,
            (const float*)d_in[2], (const float*)d_in[6], (const float*)d_in[10],
            (const float*)d_in[14], WT0, WT1, WT2, WT3, ei, cnt, slot, XC, E);
        k_scan_blk<<<NB, 1024, 0, stream>>>(cnt, offsR, bsum, bpre, done, N, NB);
        int NA = (N + 256) & ~255;
        k_finalize<<<(NA + E + 255) / 256, 256, 0, stream>>>(
            ei, offsR, bpre, slot, offs, adj, N, NB, E);
    }

    const float* as_[4] = {(const float*)d_in[3], (const float*)d_in[7],
                           (const float*)d_in[11], (const float*)d_in[15]};
    const float* ad_[4] = {(const float*)d_in[4], (const float*)d_in[8],
                           (const float*)d_in[12], (const float*)d_in[16]};
    const float* b_[4]  = {(const float*)d_in[5], (const float*)d_in[9],
                           (const float*)d_in[13], (const float*)d_in[17]};
    int H_[4] = {8, 4, 2, 1};

    const int RB  = (N + 63) / 64;         // row blocks (782)
    const int RBp = ((RB + 7) / 8) * 8;    // padded to 8 for swizzle (784)

    for (int li = 0; li < 4; ++li) {
        int H = H_[li];

        // GEMM + fused s/d (DMA-staged A/B, K-split for KT=256)
        if (li == 0) {
            k_mgemm<64, 256, 4><<<4 * RBp, 256, 0, stream>>>(
                Xb, WT0, Yb, as_[0], ad_[0], sbuf, dbuf, N, 256, H, RB);
        } else if (li == 1) {
            k_mgemm<64, 256, 2><<<2 * RBp, 256, 0, stream>>>(
                Xb, WT1, Yb, as_[1], ad_[1], sbuf, dbuf, N, 128, H, RB);
        } else if (li == 2) {
            k_mgemm<64, 128, 1><<<RBp, 256, 0, stream>>>(
                Xb, WT2, Yb, as_[2], ad_[2], sbuf, dbuf, N, 64, H, RB);
        } else {
            k_mgemm<32, 64, 1><<<RBp, 256, 0, stream>>>(
                Xb, WT3, Yb, as_[3], ad_[3], sbuf, dbuf, N, 32, H, RB);
        }
        // aggregate (+elu->bf16 for layers 0-2; +log_softmax->d_out for layer 3)
        {
            long total = (long)N * H * 4;
            int nb = (int)((total + 255) / 256);
            if (li < 3)
                k_aggf<1><<<nb, 256, 0, stream>>>(Yb, sbuf, dbuf, offs, adj, b_[li],
                                                  Xb, nullptr, N, H);
            else
                k_aggf<0><<<nb, 256, 0, stream>>>(Yb, sbuf, dbuf, offs, adj, b_[li],
                                                  nullptr, (float*)d_out, N, H);
        }
    }
}